// Round 9
// baseline (944.720 us; speedup 1.0000x reference)
//
#include <hip/hip_runtime.h>
#include <hip/hip_fp16.h>
#include <math.h>

#define BB 512   // batch
#define TT 1024  // max seq len
#define HH 128   // hidden

typedef _Float16 half2_t __attribute__((ext_vector_type(2)));

// ---------------------------------------------------------------------------
// Kernel 1: bitonic sort of (length, idx) composite keys, descending.
// Block j of the main kernel takes slots 2j, 2j+1 (similar-length pair).
// ---------------------------------------------------------------------------
__global__ __launch_bounds__(512) void sort_kernel(const int* __restrict__ lengths,
                                                   int* __restrict__ order) {
  __shared__ int comp[BB];
  const int t = threadIdx.x;
  comp[t] = (lengths[t] << 9) | t;  // unique composite keys
  __syncthreads();
  for (int k = 2; k <= BB; k <<= 1) {
    for (int j = k >> 1; j > 0; j >>= 1) {
      int ixj = t ^ j;
      if (ixj > t) {
        int a = comp[t], b = comp[ixj];
        bool descBlock = ((t & k) == 0);
        bool doSwap = descBlock ? (a < b) : (a > b);
        if (doSwap) { comp[t] = b; comp[ixj] = a; }
      }
      __syncthreads();
    }
  }
  order[t] = comp[t] & 511;
}

// 2-MAC mixed-precision dot: acc += w.lo*h.lo + w.hi*h.hi (fp32 accumulate).
// NON-volatile so the scheduler can interleave freely (r7/r8 lesson).
__device__ __forceinline__ float fdot2u(unsigned int w, unsigned int h, float acc) {
#if __has_builtin(__builtin_amdgcn_fdot2)
  return __builtin_amdgcn_fdot2(__builtin_bit_cast(half2_t, w),
                                __builtin_bit_cast(half2_t, h), acc, false);
#else
  asm("v_dot2_f32_f16 %0, %1, %2, %0" : "+v"(acc) : "v"(w), "v"(h));
  return acc;
#endif
}

// ---------------------------------------------------------------------------
// Kernel 2: GRU recurrence. 256 blocks x 1024 threads, TWO batches concurrent
// per block (sorted-adjacent pair -> block steps = max(lenA,lenB); wall time
// = longest sequence ~1024 steps instead of r1-r8's 2050).
// Phase 1: thread (i=tid&127, kc=tid>>7) does 48 v_dot2 (16 k x 3 gates,
//          both batches) on 24 packed-fp16 weight dwords shared across the
//          two batches. h operand read as packed fp16 from LDS (ping-pong).
// Phase 2: threads 0..255 = (batch, row): reduce 8 partials/gate, gates in
//          fp32, h master state in REGISTER (fp32, never quantized in the
//          z*h term), write fp16 mirror for next step's phase 1.
// ---------------------------------------------------------------------------
__global__ __launch_bounds__(1024)
__attribute__((amdgpu_waves_per_eu(4, 4)))
void gru_main(
    const float* __restrict__ x, const int* __restrict__ lengths,
    const float* __restrict__ w_ih, const float* __restrict__ w_hh,
    const float* __restrict__ b_ih, const float* __restrict__ b_hh,
    const float* __restrict__ head_w, const float* __restrict__ head_b,
    const int* __restrict__ order, float* __restrict__ out) {
  __shared__ float parts[2][3][8][HH];             // [batch][gate][kc][row] 24 KB
  __shared__ __align__(16) float xab[2][TT * 2];   // staged x rows, 16 KB
  __shared__ __align__(16) _Float16 hs16[2][2][HH];// [pingpong][batch][row]
  __shared__ float cbuf[HH * 11];                  // per-row gate constants

  const int tid = threadIdx.x;
  const int i  = tid & (HH - 1);   // row within a gate
  const int kc = tid >> 7;         // k-chunk 0..7 (16 k-elems), wave-uniform

  const int bA = order[2 * blockIdx.x + 0];
  const int bB = order[2 * blockIdx.x + 1];
  const int lenA = lengths[bA];
  const int lenB = lengths[bB];
  const int maxlen = lenA > lenB ? lenA : lenB;

  // --- one-time: weights -> packed fp16 pairs (24 dwords), pinned ---
  unsigned int wp[3][8];  // wp[g][q] = { w_hh[g*128+i][kc*16+2q], ..+2q+1 }
#pragma unroll
  for (int g = 0; g < 3; ++g)
#pragma unroll
    for (int q = 0; q < 8; ++q) {
      half2_t v;
      v.x = (_Float16)w_hh[(g * HH + i) * HH + kc * 16 + 2 * q + 0];
      v.y = (_Float16)w_hh[(g * HH + i) * HH + kc * 16 + 2 * q + 1];
      wp[g][q] = __builtin_bit_cast(unsigned int, v);
      asm volatile("" : "+v"(wp[g][q]));  // opaque def (no remat/sink)
    }

  // --- one-time: per-row gate constants into LDS (stride 11: conflict-free) ---
  if (tid < HH) {
    float* cb = &cbuf[tid * 11];
    cb[0] = w_ih[(0 * HH + tid) * 2 + 0];
    cb[1] = w_ih[(1 * HH + tid) * 2 + 0];
    cb[2] = w_ih[(2 * HH + tid) * 2 + 0];
    cb[3] = w_ih[(0 * HH + tid) * 2 + 1];
    cb[4] = w_ih[(1 * HH + tid) * 2 + 1];
    cb[5] = w_ih[(2 * HH + tid) * 2 + 1];
    cb[6] = b_ih[0 * HH + tid] + b_hh[0 * HH + tid];
    cb[7] = b_ih[1 * HH + tid] + b_hh[1 * HH + tid];
    cb[8] = b_ih[2 * HH + tid];
    cb[9] = b_hh[2 * HH + tid];
    cb[10] = head_w[tid];
  }

  // --- stage both batches' x rows (coalesced) + init fp16 h mirror ---
  for (int ofs = tid; ofs < lenA * 2; ofs += 1024)
    xab[0][ofs] = x[(size_t)bA * (TT * 2) + ofs];
  for (int ofs = tid; ofs < lenB * 2; ofs += 1024)
    xab[1][ofs] = x[(size_t)bB * (TT * 2) + ofs];
  if (tid < 2 * HH) hs16[0][tid >> 7][tid & (HH - 1)] = (_Float16)0.f;
  __syncthreads();

  const int mylen = (tid < HH) ? lenA : lenB;  // phase-2 threads only
  float hreg = 0.f;                            // fp32 master h (phase-2 rows)
  int cur = 0;

  for (int t = 0; t < maxlen; ++t) {
    // ---- phase 1: both batches' split-K matvec, packed fp16 dot2 ----
#pragma unroll
    for (int bb = 0; bb < 2; ++bb) {
      const char* hb = (const char*)(&hs16[cur][bb][0]) + kc * 32;
      const uint4 u0 = *reinterpret_cast<const uint4*>(hb);       // broadcast
      const uint4 u1 = *reinterpret_cast<const uint4*>(hb + 16);  // broadcast
      const unsigned int hp[8] = {u0.x, u0.y, u0.z, u0.w,
                                  u1.x, u1.y, u1.z, u1.w};
      float pr = 0.f, pz = 0.f, pn = 0.f;
#pragma unroll
      for (int q = 0; q < 8; ++q) {
        pr = fdot2u(wp[0][q], hp[q], pr);
        pz = fdot2u(wp[1][q], hp[q], pz);
        pn = fdot2u(wp[2][q], hp[q], pn);
      }
      parts[bb][0][kc][i] = pr;
      parts[bb][1][kc][i] = pz;
      parts[bb][2][kc][i] = pn;
    }
    __syncthreads();

    // ---- phase 2: 256 threads = (batch, row); gates fp32; h in register ----
    if (tid < 2 * HH) {
      const int bb = tid >> 7;
      const int row = tid & (HH - 1);
      float gr = 0.f, gz = 0.f, gn = 0.f;
#pragma unroll
      for (int c = 0; c < 8; ++c) gr += parts[bb][0][c][row];
#pragma unroll
      for (int c = 0; c < 8; ++c) gz += parts[bb][1][c][row];
#pragma unroll
      for (int c = 0; c < 8; ++c) gn += parts[bb][2][c][row];
      const float* cb = &cbuf[row * 11];
      const float x0 = xab[bb][2 * t + 0];
      const float x1 = xab[bb][2 * t + 1];
      const float ar = cb[6] + x0 * cb[0] + x1 * cb[3] + gr;
      const float az = cb[7] + x0 * cb[1] + x1 * cb[4] + gz;
      const float an = cb[8] + x0 * cb[2] + x1 * cb[5];
      const float hn = gn + cb[9];
      const float r = 1.0f / (1.0f + __expf(-ar));
      const float z = 1.0f / (1.0f + __expf(-az));
      const float a = an + r * hn;          // tanh argument
      const float e2 = __expf(-2.0f * a);
      const float n = (1.0f - e2) / (1.0f + e2);
      const float hnew = (1.0f - z) * n + z * hreg;
      if (t < mylen) hreg = hnew;           // freeze after this batch's end
      hs16[cur ^ 1][bb][row] = (_Float16)hreg;  // fp16 mirror for phase 1
    }
    __syncthreads();
    cur ^= 1;
  }

  // ---- head: out[b] = dot(h, head_w) + head_b, per batch ----
  if (tid < 2 * HH)
    parts[tid >> 7][0][0][tid & (HH - 1)] = hreg * cbuf[(tid & (HH - 1)) * 11 + 10];
  __syncthreads();
  if (tid < 2) {
    float s = head_b[0];
    for (int q = 0; q < HH; ++q) s += parts[tid][0][0][q];
    out[tid ? bB : bA] = s;
  }
}

extern "C" void kernel_launch(void* const* d_in, const int* in_sizes, int n_in,
                              void* d_out, int out_size, void* d_ws, size_t ws_size,
                              hipStream_t stream) {
  const float* x       = (const float*)d_in[0];
  const int*   lengths = (const int*)d_in[1];
  const float* w_ih    = (const float*)d_in[2];
  const float* w_hh    = (const float*)d_in[3];
  const float* b_ih    = (const float*)d_in[4];
  const float* b_hh    = (const float*)d_in[5];
  const float* head_w  = (const float*)d_in[6];
  const float* head_b  = (const float*)d_in[7];
  float* out = (float*)d_out;
  int* order = (int*)d_ws;  // 512 ints of scratch

  sort_kernel<<<1, 512, 0, stream>>>(lengths, order);
  gru_main<<<256, 1024, 0, stream>>>(x, lengths, w_ih, w_hh, b_ih, b_hh,
                                     head_w, head_b, order, out);
}